// Round 9
// baseline (437.928 us; speedup 1.0000x reference)
//
#include <hip/hip_runtime.h>
#include <hip/hip_bf16.h>
#include <stdint.h>

#define CDIM 768
#define HDIM 48

typedef float  f32x4  __attribute__((ext_vector_type(4)));
typedef short  bf16x8 __attribute__((ext_vector_type(8)));
typedef unsigned short u16x4 __attribute__((ext_vector_type(4)));

__device__ __forceinline__ unsigned short f2bf(float x) {
    __hip_bfloat16 h = __float2bfloat16(x);   // HW RNE convert
    return *reinterpret_cast<unsigned short*>(&h);
}
#define SB0() __builtin_amdgcn_sched_barrier(0)

__device__ __forceinline__ void gload_lds16(const void* g, void* l) {
    __builtin_amdgcn_global_load_lds(
        (const __attribute__((address_space(1))) unsigned int*)g,
        (__attribute__((address_space(3))) unsigned int*)l, 16, 0, 0);
}

// ---------------- prep: pack weights into MFMA fragment order ----------------
// (unchanged — verified correct since R1)
__global__ __launch_bounds__(256) void prep_kernel(
    const float* __restrict__ W1, const float* __restrict__ b1,
    const float* __restrict__ W2,
    const float* __restrict__ gamma, const float* __restrict__ beta,
    unsigned short* __restrict__ w1p, unsigned short* __restrict__ w2p,
    float* __restrict__ b1p, float* __restrict__ cs1)
{
    const int blk = blockIdx.x, tid = threadIdx.x;
    const int l = tid & 63;
    if (blk < 18) {                       // 72 W1 frags, 4/block
        const int fid = blk * 4 + (tid >> 6);
        const int kt = fid / 3, nt = fid % 3;
        const int k0 = kt * 32 + 8 * (l >> 4);
        const int n  = nt * 16 + (l & 15);
        bf16x8 v;
        #pragma unroll
        for (int b = 0; b < 8; ++b) {
            const int k = k0 + b;
            v[b] = (short)f2bf(gamma[k] * W1[k * HDIM + n]);
        }
        *reinterpret_cast<bf16x8*>(w1p + (size_t)(fid * 64 + l) * 8) = v;
    } else if (blk < 42) {                // 96 W2 frags, 4/block
        const int fid = (blk - 18) * 4 + (tid >> 6);
        const int kt = fid / 48, nt = fid % 48;
        const int k0 = kt * 32 + 8 * (l >> 4);
        const int n  = nt * 16 + (l & 15);
        bf16x8 v;
        #pragma unroll
        for (int b = 0; b < 8; ++b) {
            const int k = k0 + b;
            const float w = (k < HDIM) ? W2[k * CDIM + n] : 0.0f;
            v[b] = (short)f2bf(w);
        }
        *reinterpret_cast<bf16x8*>(w2p + (size_t)(fid * 64 + l) * 8) = v;
    } else {                              // b1p / cs1 reductions
        const int j = tid >> 2, p = tid & 3;
        float sb = 0.f, sg = 0.f;
        if (j < HDIM) {
            for (int c = p * 192; c < (p + 1) * 192; ++c) {
                const float w = W1[c * HDIM + j];
                sb += beta[c]  * w;
                sg += gamma[c] * w;
            }
        }
        sb += __shfl_xor(sb, 1); sb += __shfl_xor(sb, 2);
        sg += __shfl_xor(sg, 1); sg += __shfl_xor(sg, 2);
        if (p == 0 && j < HDIM) { b1p[j] = b1[j] + sb; cs1[j] = sg; }
    }
}

// ================= K1: LN + GEMM1 + QuickGELU  (x -> hid bf16) =================
// R8's barrier-free per-wave DMA pipeline, GEMM2 state stripped. Nearly pure
// read stream: 403 MB in, 17 MB out. hid stored [row][64] bf16 (k-pad zeroed).
__global__ __launch_bounds__(256, 2) void gemm1_kernel(
    const float* __restrict__ x,
    const unsigned short* __restrict__ w1p,
    const float* __restrict__ b1p,
    const float* __restrict__ cs1,
    unsigned short* __restrict__ hidp)
{
    __shared__ __align__(16) float lds_x[4][4096];   // per-wave 16 KB (2 x 8 KB dbuf)
    __shared__ __align__(16) float lds_b1[HDIM];
    __shared__ __align__(16) float lds_cs[HDIM];

    const int tid  = threadIdx.x;
    const int w    = tid >> 6;
    const int l    = tid & 63;
    const int lrow = l & 15;
    const int lg   = l >> 4;

    if (tid < 12)       reinterpret_cast<f32x4*>(lds_b1)[tid]      = reinterpret_cast<const f32x4*>(b1p)[tid];
    else if (tid < 24)  reinterpret_cast<f32x4*>(lds_cs)[tid - 12] = reinterpret_cast<const f32x4*>(cs1)[tid - 12];
    __syncthreads();   // drains -> clean vmcnt baseline

    const bf16x8* __restrict__ w1f = reinterpret_cast<const bf16x8*>(w1p);
    const int    tile = blockIdx.x * 4 + w;
    const size_t m0   = (size_t)tile * 16;

    char* const wavebuf = (char*)&lds_x[w][0];
    const char* const xg = (const char*)x + m0 * 3072;

    // DMA source offsets: instr j covers rows {2j, 2j+1}; lane row r = 2j+(l>>5);
    // phys granule (l&31) holds logical granule (l&31)^(r&7)  [involution]
    int srcoff[8];
    #pragma unroll
    for (int j = 0; j < 8; ++j) {
        const int r = 2 * j + (l >> 5);
        srcoff[j] = r * 3072 + ((((l & 31) ^ (r & 7))) << 4);
    }

    // prologue: pairs 0,1 ([w:12, x:8] each; 20 vmem ops per pair)
    bf16x8 wq[2][12];
    #pragma unroll
    for (int i = 0; i < 2; ++i) {
        #pragma unroll
        for (int q = 0; q < 12; ++q) wq[i][q] = w1f[(i * 12 + q) * 64 + l];
        #pragma unroll
        for (int j = 0; j < 8; ++j)
            gload_lds16(xg + i * 512 + srcoff[j], wavebuf + i * 8192 + j * 1024);
    }
    SB0();

    const int rowb = lrow * 512;
    const int rx   = (lrow & 7) << 4;

    f32x4 acc1[3];
    #pragma unroll
    for (int nt = 0; nt < 3; ++nt) { acc1[nt][0]=0.f; acc1[nt][1]=0.f; acc1[nt][2]=0.f; acc1[nt][3]=0.f; }
    float rsum = 0.f, rsq = 0.f;

    #pragma unroll
    for (int cc = 0; cc < 6; ++cc) {
        if (cc < 5) asm volatile("s_waitcnt vmcnt(20)" ::: "memory");
        else        asm volatile("s_waitcnt vmcnt(0)" ::: "memory");
        bf16x8 wv[12];
        #pragma unroll
        for (int q = 0; q < 12; ++q) wv[q] = wq[cc & 1][q];
        const char* bb = wavebuf + (cc & 1) * 8192 + rowb;
        f32x4 xr[8];
        #pragma unroll
        for (int ktl = 0; ktl < 4; ++ktl) {
            xr[2*ktl+0] = *reinterpret_cast<const f32x4*>(bb + ((ktl * 128 + lg * 32     ) ^ rx));
            xr[2*ktl+1] = *reinterpret_cast<const f32x4*>(bb + ((ktl * 128 + lg * 32 + 16) ^ rx));
        }
        asm volatile("s_waitcnt lgkmcnt(0)" ::: "memory");
        SB0();
        if (cc + 2 < 6) {
            #pragma unroll
            for (int q = 0; q < 12; ++q)
                wq[cc & 1][q] = w1f[((cc + 2) * 12 + q) * 64 + l];
            #pragma unroll
            for (int j = 0; j < 8; ++j)
                gload_lds16(xg + (cc + 2) * 512 + srcoff[j], wavebuf + (cc & 1) * 8192 + j * 1024);
        }
        SB0();
        #pragma unroll
        for (int ktl = 0; ktl < 4; ++ktl) {
            const f32x4 xa = xr[2*ktl+0];
            const f32x4 xb = xr[2*ktl+1];
            bf16x8 bf;
            #pragma unroll
            for (int b = 0; b < 4; ++b) {
                rsum += xa[b]; rsq += xa[b] * xa[b];
                rsum += xb[b]; rsq += xb[b] * xb[b];
                bf[b]     = (short)f2bf(xa[b]);
                bf[b + 4] = (short)f2bf(xb[b]);
            }
            acc1[0] = __builtin_amdgcn_mfma_f32_16x16x32_bf16(wv[ktl*3+0], bf, acc1[0], 0, 0, 0);
            acc1[1] = __builtin_amdgcn_mfma_f32_16x16x32_bf16(wv[ktl*3+1], bf, acc1[1], 0, 0, 0);
            acc1[2] = __builtin_amdgcn_mfma_f32_16x16x32_bf16(wv[ktl*3+2], bf, acc1[2], 0, 0, 0);
        }
    }

    rsum += __shfl_xor(rsum, 16); rsum += __shfl_xor(rsum, 32);
    rsq  += __shfl_xor(rsq , 16); rsq  += __shfl_xor(rsq , 32);
    const float mu   = rsum * (1.f / 768.f);
    const float var  = rsq * (1.f / 768.f) - mu * mu;
    const float rstd = rsqrtf(var + 1e-5f);

    // LN fixup + bias + QuickGELU -> hid global [row][64] bf16
    unsigned short* const hrow = hidp + (m0 + lrow) * 64;
    #pragma unroll
    for (int nt = 0; nt < 3; ++nt) {
        const int c4 = nt * 16 + 4 * lg;
        const f32x4 bb = *reinterpret_cast<const f32x4*>(&lds_b1[c4]);
        const f32x4 cs = *reinterpret_cast<const f32x4*>(&lds_cs[c4]);
        u16x4 pk;
        #pragma unroll
        for (int r = 0; r < 4; ++r) {
            const float h = rstd * (acc1[nt][r] - mu * cs[r]) + bb[r];
            const float g = h / (1.f + __expf(-1.702f * h));
            pk[r] = f2bf(g);
        }
        *reinterpret_cast<u16x4*>(hrow + c4) = pk;
    }
    u16x4 z; z[0]=0; z[1]=0; z[2]=0; z[3]=0;
    *reinterpret_cast<u16x4*>(hrow + 48 + 4 * lg) = z;   // k-pad 48..63
}

// ================= K2: GEMM2 + bias + residual  (hid,x -> out) =================
// R2's verified GEMM2 at high occupancy (low VGPR, tiny LDS). Clean 1R:1W stream.
__global__ __launch_bounds__(256, 4) void gemm2_kernel(
    const float* __restrict__ x,
    const unsigned short* __restrict__ hidp,
    const float* __restrict__ b2g,
    const unsigned short* __restrict__ w2p,
    float* __restrict__ out)
{
    __shared__ __align__(16) float lds_b2[CDIM];
    const int tid  = threadIdx.x;
    const int w    = tid >> 6;
    const int l    = tid & 63;
    const int lrow = l & 15;
    const int lg   = l >> 4;

    if (tid < 192) reinterpret_cast<f32x4*>(lds_b2)[tid] = reinterpret_cast<const f32x4*>(b2g)[tid];
    __syncthreads();

    const bf16x8* __restrict__ w2f = reinterpret_cast<const bf16x8*>(w2p);
    const int    tile = blockIdx.x * 4 + w;
    const size_t m0   = (size_t)tile * 16;

    const unsigned short* const hrow = hidp + (m0 + lrow) * 64;
    const bf16x8 a2_0 = *reinterpret_cast<const bf16x8*>(hrow + 8 * lg);
    const bf16x8 a2_1 = *reinterpret_cast<const bf16x8*>(hrow + 32 + 8 * lg);

    const float* __restrict__ xres = x   + (m0 + lrow) * CDIM;
    float* __restrict__       ores = out + (m0 + lrow) * CDIM;

    #pragma unroll 1
    for (int ch = 0; ch < 6; ++ch) {
        f32x4 res[8];
        #pragma unroll
        for (int n8 = 0; n8 < 8; ++n8)
            res[n8] = *reinterpret_cast<const f32x4*>(xres + (ch * 8 + n8) * 16 + 4 * lg);
        f32x4 acc2[8];
        #pragma unroll
        for (int n8 = 0; n8 < 8; ++n8) { acc2[n8][0]=0.f; acc2[n8][1]=0.f; acc2[n8][2]=0.f; acc2[n8][3]=0.f; }
        #pragma unroll
        for (int n8 = 0; n8 < 8; ++n8) {
            const int ct = ch * 8 + n8;
            acc2[n8] = __builtin_amdgcn_mfma_f32_16x16x32_bf16(w2f[ct * 64 + l],        a2_0, acc2[n8], 0, 0, 0);
            acc2[n8] = __builtin_amdgcn_mfma_f32_16x16x32_bf16(w2f[(48 + ct) * 64 + l], a2_1, acc2[n8], 0, 0, 0);
        }
        #pragma unroll
        for (int n8 = 0; n8 < 8; ++n8) {
            const int c4 = (ch * 8 + n8) * 16 + 4 * lg;
            const f32x4 bb = *reinterpret_cast<const f32x4*>(&lds_b2[c4]);
            f32x4 o;
            #pragma unroll
            for (int r = 0; r < 4; ++r) o[r] = acc2[n8][r] + bb[r] + res[n8][r];
            *reinterpret_cast<f32x4*>(ores + c4) = o;
        }
    }
}

// ---------------- fallback: R8 fused kernel (used only if ws too small) --------
__global__ __launch_bounds__(256, 2) void mlp_fused_kernel(
    const float* __restrict__ x,
    const float* __restrict__ b2g,
    const unsigned short* __restrict__ w1p,
    const unsigned short* __restrict__ w2p,
    const float* __restrict__ b1p,
    const float* __restrict__ cs1,
    float* __restrict__ out)
{
    __shared__ __align__(16) float lds_x[4][4096];
    __shared__ __align__(16) float lds_b2[CDIM];
    __shared__ __align__(16) float lds_b1[HDIM];
    __shared__ __align__(16) float lds_cs[HDIM];

    const int tid  = threadIdx.x;
    const int w    = tid >> 6;
    const int l    = tid & 63;
    const int lrow = l & 15;
    const int lg   = l >> 4;

    if (tid < 192)       reinterpret_cast<f32x4*>(lds_b2)[tid]       = reinterpret_cast<const f32x4*>(b2g)[tid];
    else if (tid < 204)  reinterpret_cast<f32x4*>(lds_b1)[tid - 192] = reinterpret_cast<const f32x4*>(b1p)[tid - 192];
    else if (tid < 216)  reinterpret_cast<f32x4*>(lds_cs)[tid - 204] = reinterpret_cast<const f32x4*>(cs1)[tid - 204];
    __syncthreads();

    const bf16x8* __restrict__ w1f = reinterpret_cast<const bf16x8*>(w1p);
    const bf16x8* __restrict__ w2f = reinterpret_cast<const bf16x8*>(w2p);
    const int    tile = blockIdx.x * 4 + w;
    const size_t m0   = (size_t)tile * 16;

    char* const wavebuf = (char*)&lds_x[w][0];
    const char* const xg = (const char*)x + m0 * 3072;
    int srcoff[8];
    #pragma unroll
    for (int j = 0; j < 8; ++j) {
        const int r = 2 * j + (l >> 5);
        srcoff[j] = r * 3072 + ((((l & 31) ^ (r & 7))) << 4);
    }
    bf16x8 wq[2][12];
    #pragma unroll
    for (int i = 0; i < 2; ++i) {
        #pragma unroll
        for (int q = 0; q < 12; ++q) wq[i][q] = w1f[(i * 12 + q) * 64 + l];
        #pragma unroll
        for (int j = 0; j < 8; ++j)
            gload_lds16(xg + i * 512 + srcoff[j], wavebuf + i * 8192 + j * 1024);
    }
    SB0();
    const int rowb = lrow * 512;
    const int rx   = (lrow & 7) << 4;
    f32x4 acc1[3];
    #pragma unroll
    for (int nt = 0; nt < 3; ++nt) { acc1[nt][0]=0.f; acc1[nt][1]=0.f; acc1[nt][2]=0.f; acc1[nt][3]=0.f; }
    float rsum = 0.f, rsq = 0.f;
    #pragma unroll
    for (int cc = 0; cc < 6; ++cc) {
        if (cc < 5) asm volatile("s_waitcnt vmcnt(20)" ::: "memory");
        else        asm volatile("s_waitcnt vmcnt(0)" ::: "memory");
        bf16x8 wv[12];
        #pragma unroll
        for (int q = 0; q < 12; ++q) wv[q] = wq[cc & 1][q];
        const char* bb = wavebuf + (cc & 1) * 8192 + rowb;
        f32x4 xr[8];
        #pragma unroll
        for (int ktl = 0; ktl < 4; ++ktl) {
            xr[2*ktl+0] = *reinterpret_cast<const f32x4*>(bb + ((ktl * 128 + lg * 32     ) ^ rx));
            xr[2*ktl+1] = *reinterpret_cast<const f32x4*>(bb + ((ktl * 128 + lg * 32 + 16) ^ rx));
        }
        asm volatile("s_waitcnt lgkmcnt(0)" ::: "memory");
        SB0();
        if (cc + 2 < 6) {
            #pragma unroll
            for (int q = 0; q < 12; ++q)
                wq[cc & 1][q] = w1f[((cc + 2) * 12 + q) * 64 + l];
            #pragma unroll
            for (int j = 0; j < 8; ++j)
                gload_lds16(xg + (cc + 2) * 512 + srcoff[j], wavebuf + (cc & 1) * 8192 + j * 1024);
        }
        SB0();
        #pragma unroll
        for (int ktl = 0; ktl < 4; ++ktl) {
            const f32x4 xa = xr[2*ktl+0];
            const f32x4 xb = xr[2*ktl+1];
            bf16x8 bf;
            #pragma unroll
            for (int b = 0; b < 4; ++b) {
                rsum += xa[b]; rsq += xa[b] * xa[b];
                rsum += xb[b]; rsq += xb[b] * xb[b];
                bf[b]     = (short)f2bf(xa[b]);
                bf[b + 4] = (short)f2bf(xb[b]);
            }
            acc1[0] = __builtin_amdgcn_mfma_f32_16x16x32_bf16(wv[ktl*3+0], bf, acc1[0], 0, 0, 0);
            acc1[1] = __builtin_amdgcn_mfma_f32_16x16x32_bf16(wv[ktl*3+1], bf, acc1[1], 0, 0, 0);
            acc1[2] = __builtin_amdgcn_mfma_f32_16x16x32_bf16(wv[ktl*3+2], bf, acc1[2], 0, 0, 0);
        }
    }
    rsum += __shfl_xor(rsum, 16); rsum += __shfl_xor(rsum, 32);
    rsq  += __shfl_xor(rsq , 16); rsq  += __shfl_xor(rsq , 32);
    const float mu   = rsum * (1.f / 768.f);
    const float var  = rsq * (1.f / 768.f) - mu * mu;
    const float rstd = rsqrtf(var + 1e-5f);
    unsigned short* const hid = (unsigned short*)wavebuf;
    *reinterpret_cast<unsigned long long*>(hid + (l >> 2) * 72 + 48 + (l & 3) * 4) = 0ull;
    #pragma unroll
    for (int nt = 0; nt < 3; ++nt) {
        const int c4 = nt * 16 + 4 * lg;
        const f32x4 bb = *reinterpret_cast<const f32x4*>(&lds_b1[c4]);
        const f32x4 cs = *reinterpret_cast<const f32x4*>(&lds_cs[c4]);
        u16x4 pk;
        #pragma unroll
        for (int r = 0; r < 4; ++r) {
            const float h = rstd * (acc1[nt][r] - mu * cs[r]) + bb[r];
            const float g = h / (1.f + __expf(-1.702f * h));
            pk[r] = f2bf(g);
        }
        *reinterpret_cast<u16x4*>(hid + lrow * 72 + c4) = pk;
    }
    const bf16x8 a2_0 = *reinterpret_cast<const bf16x8*>(hid + lrow * 72 + 8 * lg);
    const bf16x8 a2_1 = *reinterpret_cast<const bf16x8*>(hid + lrow * 72 + 8 * lg + 32);
    const float* __restrict__ xres = x   + (m0 + lrow) * CDIM;
    float* __restrict__       ores = out + (m0 + lrow) * CDIM;
    #pragma unroll 1
    for (int ch = 0; ch < 6; ++ch) {
        f32x4 res[8];
        #pragma unroll
        for (int n8 = 0; n8 < 8; ++n8)
            res[n8] = *reinterpret_cast<const f32x4*>(xres + (ch * 8 + n8) * 16 + 4 * lg);
        f32x4 acc2[8];
        #pragma unroll
        for (int n8 = 0; n8 < 8; ++n8) { acc2[n8][0]=0.f; acc2[n8][1]=0.f; acc2[n8][2]=0.f; acc2[n8][3]=0.f; }
        #pragma unroll
        for (int n8 = 0; n8 < 8; ++n8) {
            const int ct = ch * 8 + n8;
            acc2[n8] = __builtin_amdgcn_mfma_f32_16x16x32_bf16(w2f[ct * 64 + l],        a2_0, acc2[n8], 0, 0, 0);
            acc2[n8] = __builtin_amdgcn_mfma_f32_16x16x32_bf16(w2f[(48 + ct) * 64 + l], a2_1, acc2[n8], 0, 0, 0);
        }
        #pragma unroll
        for (int n8 = 0; n8 < 8; ++n8) {
            const int c4 = (ch * 8 + n8) * 16 + 4 * lg;
            const f32x4 bb = *reinterpret_cast<const f32x4*>(&lds_b2[c4]);
            f32x4 o;
            #pragma unroll
            for (int r = 0; r < 4; ++r) o[r] = acc2[n8][r] + bb[r] + res[n8][r];
            *reinterpret_cast<f32x4*>(ores + c4) = o;
        }
    }
}

extern "C" void kernel_launch(void* const* d_in, const int* in_sizes, int n_in,
                              void* d_out, int out_size, void* d_ws, size_t ws_size,
                              hipStream_t stream)
{
    const float* x     = (const float*)d_in[0];
    const float* W1    = (const float*)d_in[1];
    const float* b1    = (const float*)d_in[2];
    const float* W2    = (const float*)d_in[3];
    const float* b2    = (const float*)d_in[4];
    const float* gamma = (const float*)d_in[5];
    const float* beta  = (const float*)d_in[6];
    float* out = (float*)d_out;

    unsigned short* w1p = (unsigned short*)d_ws;     // 73728 B
    unsigned short* w2p = w1p + 24 * 3 * 64 * 8;     // 98304 B
    float* b1p = (float*)(w2p + 2 * 48 * 64 * 8);    // 48 f32
    float* cs1 = b1p + 64;                           // 48 f32

    const int M = in_sizes[0] / CDIM;   // 131072 rows
    const int blocks = M / 64;          // 2048

    prep_kernel<<<dim3(43), dim3(256), 0, stream>>>(W1, b1, W2, gamma, beta, w1p, w2p, b1p, cs1);

    const size_t hid_off  = 262144;                       // 256 KB, past weight packs
    const size_t hid_need = hid_off + (size_t)M * 64 * 2; // [row][64] bf16 = ~17 MB
    if (ws_size >= hid_need) {
        unsigned short* hidp = (unsigned short*)((char*)d_ws + hid_off);
        gemm1_kernel<<<dim3(blocks), dim3(256), 0, stream>>>(x, w1p, b1p, cs1, hidp);
        gemm2_kernel<<<dim3(blocks), dim3(256), 0, stream>>>(x, hidp, b2, w2p, out);
    } else {
        mlp_fused_kernel<<<dim3(blocks), dim3(256), 0, stream>>>(x, b2, w1p, w2p, b1p, cs1, out);
    }
}

// Round 10
// 307.290 us; speedup vs baseline: 1.4251x; 1.4251x over previous
//
#include <hip/hip_runtime.h>
#include <hip/hip_bf16.h>
#include <stdint.h>

#define CDIM 768
#define HDIM 48

typedef float  f32x4  __attribute__((ext_vector_type(4)));
typedef short  bf16x8 __attribute__((ext_vector_type(8)));
typedef unsigned short u16x4 __attribute__((ext_vector_type(4)));

__device__ __forceinline__ unsigned short f2bf(float x) {
    __hip_bfloat16 h = __float2bfloat16(x);   // HW RNE convert
    return *reinterpret_cast<unsigned short*>(&h);
}

// ---------------- prep: pack weights into MFMA fragment order ----------------
// (unchanged — verified correct since R1)
__global__ __launch_bounds__(256) void prep_kernel(
    const float* __restrict__ W1, const float* __restrict__ b1,
    const float* __restrict__ W2,
    const float* __restrict__ gamma, const float* __restrict__ beta,
    unsigned short* __restrict__ w1p, unsigned short* __restrict__ w2p,
    float* __restrict__ b1p, float* __restrict__ cs1)
{
    const int blk = blockIdx.x, tid = threadIdx.x;
    const int l = tid & 63;
    if (blk < 18) {                       // 72 W1 frags, 4/block
        const int fid = blk * 4 + (tid >> 6);
        const int kt = fid / 3, nt = fid % 3;
        const int k0 = kt * 32 + 8 * (l >> 4);
        const int n  = nt * 16 + (l & 15);
        bf16x8 v;
        #pragma unroll
        for (int b = 0; b < 8; ++b) {
            const int k = k0 + b;
            v[b] = (short)f2bf(gamma[k] * W1[k * HDIM + n]);
        }
        *reinterpret_cast<bf16x8*>(w1p + (size_t)(fid * 64 + l) * 8) = v;
    } else if (blk < 42) {                // 96 W2 frags, 4/block
        const int fid = (blk - 18) * 4 + (tid >> 6);
        const int kt = fid / 48, nt = fid % 48;
        const int k0 = kt * 32 + 8 * (l >> 4);
        const int n  = nt * 16 + (l & 15);
        bf16x8 v;
        #pragma unroll
        for (int b = 0; b < 8; ++b) {
            const int k = k0 + b;
            const float w = (k < HDIM) ? W2[k * CDIM + n] : 0.0f;
            v[b] = (short)f2bf(w);
        }
        *reinterpret_cast<bf16x8*>(w2p + (size_t)(fid * 64 + l) * 8) = v;
    } else {                              // b1p / cs1 reductions
        const int j = tid >> 2, p = tid & 3;
        float sb = 0.f, sg = 0.f;
        if (j < HDIM) {
            for (int c = p * 192; c < (p + 1) * 192; ++c) {
                const float w = W1[c * HDIM + j];
                sb += beta[c]  * w;
                sg += gamma[c] * w;
            }
        }
        sb += __shfl_xor(sb, 1); sb += __shfl_xor(sb, 2);
        sg += __shfl_xor(sg, 1); sg += __shfl_xor(sg, 2);
        if (p == 0 && j < HDIM) { b1p[j] = b1[j] + sb; cs1[j] = sg; }
    }
}

// ---------------- main fused kernel ----------------
// R10: GEMM1 restructured to MIRROR the measured-fast GEMM2 shape (split-K2,
// 4.4 TB/s): per chunk, burst 8 independent plain f32x4 x-loads for the NEXT
// chunk (rotating pv/xv register arrays, statically indexed, unroll-1 loop),
// then compute this chunk with W1 fragments loaded just-in-time. No inline
// asm, no global_load_lds, no LDS staging of x, no sched_barrier — the
// compiler's natural schedule is what achieved 4.4 TB/s in K2. While the wave
// stalls (L2 weight loads / MFMA), its 8 posted HBM loads keep the memory
// system fed — the property every slow GEMM1 variant lacked.
__global__ __launch_bounds__(256, 2) void mlp_kernel(
    const float* __restrict__ x,
    const float* __restrict__ b2g,
    const unsigned short* __restrict__ w1p,
    const unsigned short* __restrict__ w2p,
    const float* __restrict__ b1p,
    const float* __restrict__ cs1,
    float* __restrict__ out)
{
    __shared__ __align__(16) unsigned short lds_hid[4][16][72]; // stride 72 -> 2-way banks (free)
    __shared__ __align__(16) float lds_b2[CDIM];
    __shared__ __align__(16) float lds_b1[HDIM];
    __shared__ __align__(16) float lds_cs[HDIM];

    const int tid  = threadIdx.x;
    const int w    = tid >> 6;
    const int l    = tid & 63;
    const int lrow = l & 15;    // row within this wave's 16-row tile
    const int lg   = l >> 4;    // 8-col group within a 32-wide ktile

    // one-time const staging
    if (tid < 192)       reinterpret_cast<f32x4*>(lds_b2)[tid]       = reinterpret_cast<const f32x4*>(b2g)[tid];
    else if (tid < 204)  reinterpret_cast<f32x4*>(lds_b1)[tid - 192] = reinterpret_cast<const f32x4*>(b1p)[tid - 192];
    else if (tid < 216)  reinterpret_cast<f32x4*>(lds_cs)[tid - 204] = reinterpret_cast<const f32x4*>(cs1)[tid - 204];
    // zero the k-pad region (cols 48..63) of this wave's hid tile
    *reinterpret_cast<unsigned long long*>(&lds_hid[w][l >> 2][48 + (l & 3) * 4]) = 0ull;
    __syncthreads();

    const bf16x8* __restrict__ w1f = reinterpret_cast<const bf16x8*>(w1p);
    const bf16x8* __restrict__ w2f = reinterpret_cast<const bf16x8*>(w2p);

    const int    tile = blockIdx.x * 4 + w;
    const size_t m0   = (size_t)tile * 16;
    const float* __restrict__ xrow = x + (m0 + lrow) * CDIM + 8 * lg;

    // ================= GEMM1: hid_raw = x @ W1'  (+ fused row stats) =========
    // chunk = 4 ktiles = 128 cols; lane reads 8 x f32x4 (independent burst)
    f32x4 pv[8];
    #pragma unroll
    for (int j = 0; j < 8; ++j)
        pv[j] = *reinterpret_cast<const f32x4*>(xrow + (j >> 1) * 32 + (j & 1) * 4);

    f32x4 acc1[3];
    #pragma unroll
    for (int nt = 0; nt < 3; ++nt) { acc1[nt][0]=0.f; acc1[nt][1]=0.f; acc1[nt][2]=0.f; acc1[nt][3]=0.f; }
    float rsum = 0.f, rsq = 0.f;

    #pragma unroll 1
    for (int ch = 0; ch < 6; ++ch) {
        // burst-issue next chunk's 8 loads (clamped on last iter; L2-hit rereads)
        const int chn = (ch + 1 < 6) ? ch + 1 : 5;
        f32x4 xv[8];
        #pragma unroll
        for (int j = 0; j < 8; ++j)
            xv[j] = *reinterpret_cast<const f32x4*>(xrow + chn * 128 + (j >> 1) * 32 + (j & 1) * 4);

        // compute THIS chunk: 4 ktiles, weights just-in-time (L2-resident)
        #pragma unroll
        for (int ktl = 0; ktl < 4; ++ktl) {
            const int kt = ch * 4 + ktl;
            const bf16x8 wv0 = w1f[(kt * 3 + 0) * 64 + l];
            const bf16x8 wv1 = w1f[(kt * 3 + 1) * 64 + l];
            const bf16x8 wv2 = w1f[(kt * 3 + 2) * 64 + l];
            const f32x4 xa = pv[2 * ktl + 0];
            const f32x4 xb = pv[2 * ktl + 1];
            bf16x8 bf;
            #pragma unroll
            for (int b = 0; b < 4; ++b) {
                rsum += xa[b]; rsq += xa[b] * xa[b];
                rsum += xb[b]; rsq += xb[b] * xb[b];
                bf[b]     = (short)f2bf(xa[b]);
                bf[b + 4] = (short)f2bf(xb[b]);
            }
            acc1[0] = __builtin_amdgcn_mfma_f32_16x16x32_bf16(wv0, bf, acc1[0], 0, 0, 0);
            acc1[1] = __builtin_amdgcn_mfma_f32_16x16x32_bf16(wv1, bf, acc1[1], 0, 0, 0);
            acc1[2] = __builtin_amdgcn_mfma_f32_16x16x32_bf16(wv2, bf, acc1[2], 0, 0, 0);
        }
        // rotate (SSA copies; statically indexed -> stays in registers)
        #pragma unroll
        for (int j = 0; j < 8; ++j) pv[j] = xv[j];
    }

    rsum += __shfl_xor(rsum, 16); rsum += __shfl_xor(rsum, 32);
    rsq  += __shfl_xor(rsq , 16); rsq  += __shfl_xor(rsq , 32);
    const float mu   = rsum * (1.f / 768.f);
    const float var  = rsq * (1.f / 768.f) - mu * mu;
    const float rstd = rsqrtf(var + 1e-5f);

    // ---- LN fixup + bias + QuickGELU -> LDS bf16 ----
    #pragma unroll
    for (int nt = 0; nt < 3; ++nt) {
        const int c4 = nt * 16 + 4 * lg;
        const f32x4 bb = *reinterpret_cast<const f32x4*>(&lds_b1[c4]);
        const f32x4 cs = *reinterpret_cast<const f32x4*>(&lds_cs[c4]);
        u16x4 pk;
        #pragma unroll
        for (int r = 0; r < 4; ++r) {
            const float h = rstd * (acc1[nt][r] - mu * cs[r]) + bb[r];
            const float g = h / (1.f + __expf(-1.702f * h));
            pk[r] = f2bf(g);
        }
        *reinterpret_cast<u16x4*>(&lds_hid[w][lrow][c4]) = pk;
    }
    // wave-synchronous LDS handoff (same wave writes+reads; lgkmcnt-ordered)
    const bf16x8 a2_0 = *reinterpret_cast<const bf16x8*>(&lds_hid[w][lrow][8 * lg]);
    const bf16x8 a2_1 = *reinterpret_cast<const bf16x8*>(&lds_hid[w][lrow][8 * lg + 32]);

    const float* __restrict__ xres = x   + (m0 + lrow) * CDIM;
    float* __restrict__       ores = out + (m0 + lrow) * CDIM;

    // ===== GEMM2 (R2-verbatim, measured 4.4 TB/s standalone) =====
    #pragma unroll 1
    for (int ch = 0; ch < 6; ++ch) {
        f32x4 res[8];
        #pragma unroll
        for (int n8 = 0; n8 < 8; ++n8)
            res[n8] = *reinterpret_cast<const f32x4*>(xres + (ch * 8 + n8) * 16 + 4 * lg);
        f32x4 acc2[8];
        #pragma unroll
        for (int n8 = 0; n8 < 8; ++n8) { acc2[n8][0]=0.f; acc2[n8][1]=0.f; acc2[n8][2]=0.f; acc2[n8][3]=0.f; }
        #pragma unroll
        for (int n8 = 0; n8 < 8; ++n8) {
            const int ct = ch * 8 + n8;
            acc2[n8] = __builtin_amdgcn_mfma_f32_16x16x32_bf16(w2f[ct * 64 + l],        a2_0, acc2[n8], 0, 0, 0);
            acc2[n8] = __builtin_amdgcn_mfma_f32_16x16x32_bf16(w2f[(48 + ct) * 64 + l], a2_1, acc2[n8], 0, 0, 0);
        }
        #pragma unroll
        for (int n8 = 0; n8 < 8; ++n8) {
            const int c4 = (ch * 8 + n8) * 16 + 4 * lg;
            const f32x4 bb = *reinterpret_cast<const f32x4*>(&lds_b2[c4]);
            f32x4 o;
            #pragma unroll
            for (int r = 0; r < 4; ++r) o[r] = acc2[n8][r] + bb[r] + res[n8][r];
            *reinterpret_cast<f32x4*>(ores + c4) = o;
        }
    }
}

extern "C" void kernel_launch(void* const* d_in, const int* in_sizes, int n_in,
                              void* d_out, int out_size, void* d_ws, size_t ws_size,
                              hipStream_t stream)
{
    const float* x     = (const float*)d_in[0];
    const float* W1    = (const float*)d_in[1];
    const float* b1    = (const float*)d_in[2];
    const float* W2    = (const float*)d_in[3];
    const float* b2    = (const float*)d_in[4];
    const float* gamma = (const float*)d_in[5];
    const float* beta  = (const float*)d_in[6];
    float* out = (float*)d_out;

    unsigned short* w1p = (unsigned short*)d_ws;     // 72 frags * 512 B  = 73728 B
    unsigned short* w2p = w1p + 24 * 3 * 64 * 8;     // 96 frags * 512 B  = 98304 B
    float* b1p = (float*)(w2p + 2 * 48 * 64 * 8);    // 48 f32
    float* cs1 = b1p + 64;                           // 48 f32 (16B-aligned gap)

    const int M = in_sizes[0] / CDIM;   // 131072 rows
    const int blocks = M / 64;          // 2048 blocks x 4 waves x 16 rows

    prep_kernel<<<dim3(43), dim3(256), 0, stream>>>(W1, b1, W2, gamma, beta, w1p, w2p, b1p, cs1);
    mlp_kernel<<<dim3(blocks), dim3(256), 0, stream>>>(x, b2, w1p, w2p, b1p, cs1, out);
}

// Round 11
// 254.181 us; speedup vs baseline: 1.7229x; 1.2089x over previous
//
#include <hip/hip_runtime.h>
#include <hip/hip_bf16.h>
#include <stdint.h>

#define CDIM 768
#define HDIM 48

typedef float  f32x4  __attribute__((ext_vector_type(4)));
typedef short  bf16x8 __attribute__((ext_vector_type(8)));
typedef unsigned short u16x4 __attribute__((ext_vector_type(4)));

__device__ __forceinline__ unsigned short f2bf(float x) {
    __hip_bfloat16 h = __float2bfloat16(x);   // HW RNE convert
    return *reinterpret_cast<unsigned short*>(&h);
}

// ---------------- prep: pack weights into MFMA fragment order ----------------
// (unchanged — verified correct since R1)
__global__ __launch_bounds__(256) void prep_kernel(
    const float* __restrict__ W1, const float* __restrict__ b1,
    const float* __restrict__ W2,
    const float* __restrict__ gamma, const float* __restrict__ beta,
    unsigned short* __restrict__ w1p, unsigned short* __restrict__ w2p,
    float* __restrict__ b1p, float* __restrict__ cs1)
{
    const int blk = blockIdx.x, tid = threadIdx.x;
    const int l = tid & 63;
    if (blk < 18) {                       // 72 W1 frags, 4/block
        const int fid = blk * 4 + (tid >> 6);
        const int kt = fid / 3, nt = fid % 3;
        const int k0 = kt * 32 + 8 * (l >> 4);
        const int n  = nt * 16 + (l & 15);
        bf16x8 v;
        #pragma unroll
        for (int b = 0; b < 8; ++b) {
            const int k = k0 + b;
            v[b] = (short)f2bf(gamma[k] * W1[k * HDIM + n]);
        }
        *reinterpret_cast<bf16x8*>(w1p + (size_t)(fid * 64 + l) * 8) = v;
    } else if (blk < 42) {                // 96 W2 frags, 4/block
        const int fid = (blk - 18) * 4 + (tid >> 6);
        const int kt = fid / 48, nt = fid % 48;
        const int k0 = kt * 32 + 8 * (l >> 4);
        const int n  = nt * 16 + (l & 15);
        bf16x8 v;
        #pragma unroll
        for (int b = 0; b < 8; ++b) {
            const int k = k0 + b;
            const float w = (k < HDIM) ? W2[k * CDIM + n] : 0.0f;
            v[b] = (short)f2bf(w);
        }
        *reinterpret_cast<bf16x8*>(w2p + (size_t)(fid * 64 + l) * 8) = v;
    } else {                              // b1p / cs1 reductions
        const int j = tid >> 2, p = tid & 3;
        float sb = 0.f, sg = 0.f;
        if (j < HDIM) {
            for (int c = p * 192; c < (p + 1) * 192; ++c) {
                const float w = W1[c * HDIM + j];
                sb += beta[c]  * w;
                sg += gamma[c] * w;
            }
        }
        sb += __shfl_xor(sb, 1); sb += __shfl_xor(sb, 2);
        sg += __shfl_xor(sg, 1); sg += __shfl_xor(sg, 2);
        if (p == 0 && j < HDIM) { b1p[j] = b1[j] + sb; cs1[j] = sg; }
    }
}

// ---------------- main fused kernel ----------------
// R11: W1 fragment pack staged in LDS once per block (cooperative, 73.7 KB).
// GEMM1's vmem FIFO then carries ONLY the x stream (frags come via
// ds_read_b128 / lgkmcnt — separate counter & HW path), so x-load retirement
// is never blocked by fragment loads and the CU request window is pure-x.
// Fragment L2 traffic drops 16x (72KB/wave -> 18KB per 4-wave block).
// hid tile aliases the W1 LDS region after a barrier. GEMM2 keeps global
// w2 frags (that phase measured 4.4 TB/s standalone in R9).
__global__ __launch_bounds__(256, 2) void mlp_kernel(
    const float* __restrict__ x,
    const float* __restrict__ b2g,
    const unsigned short* __restrict__ w1p,
    const unsigned short* __restrict__ w2p,
    const float* __restrict__ b1p,
    const float* __restrict__ cs1,
    float* __restrict__ out)
{
    __shared__ __align__(16) char  lds_big[73728];   // W1 pack; later hid[4][16][72]
    __shared__ __align__(16) float lds_b2[CDIM];
    __shared__ __align__(16) float lds_b1[HDIM];
    __shared__ __align__(16) float lds_cs[HDIM];

    const int tid  = threadIdx.x;
    const int w    = tid >> 6;
    const int l    = tid & 63;
    const int lrow = l & 15;    // row within this wave's 16-row tile
    const int lg   = l >> 4;    // 8-col group within a 32-wide ktile

    // one-time const staging
    if (tid < 192)       reinterpret_cast<f32x4*>(lds_b2)[tid]       = reinterpret_cast<const f32x4*>(b2g)[tid];
    else if (tid < 204)  reinterpret_cast<f32x4*>(lds_b1)[tid - 192] = reinterpret_cast<const f32x4*>(b1p)[tid - 192];
    else if (tid < 216)  reinterpret_cast<f32x4*>(lds_cs)[tid - 204] = reinterpret_cast<const f32x4*>(cs1)[tid - 204];

    // cooperative W1-pack load: 73728 B = 4608 x 16B, 18 per thread, coalesced
    {
        const f32x4* __restrict__ src = reinterpret_cast<const f32x4*>(w1p);
        f32x4* __restrict__ dst = reinterpret_cast<f32x4*>(lds_big);
        #pragma unroll
        for (int i = 0; i < 18; ++i)
            dst[tid + i * 256] = src[tid + i * 256];
    }
    __syncthreads();

    const bf16x8* __restrict__ w1l = reinterpret_cast<const bf16x8*>(lds_big);   // LDS frags
    const bf16x8* __restrict__ w2f = reinterpret_cast<const bf16x8*>(w2p);       // global frags

    const int    tile = blockIdx.x * 4 + w;
    const size_t m0   = (size_t)tile * 16;
    const float* __restrict__ xrow = x + (m0 + lrow) * CDIM + 8 * lg;

    // ================= GEMM1: hid_raw = x @ W1'  (+ fused row stats) =========
    f32x4 acc1[3];
    #pragma unroll
    for (int nt = 0; nt < 3; ++nt) { acc1[nt][0]=0.f; acc1[nt][1]=0.f; acc1[nt][2]=0.f; acc1[nt][3]=0.f; }
    float rs0 = 0.f, rs1 = 0.f, rq0 = 0.f, rq1 = 0.f;   // split chains

    #pragma unroll 1
    for (int ch = 0; ch < 6; ++ch) {
        // burst 8 independent x-loads for THIS chunk (pure-x vmcnt FIFO;
        // compiler inserts progressive waits — nothing else in the queue)
        f32x4 xv[8];
        #pragma unroll
        for (int j = 0; j < 8; ++j)
            xv[j] = *reinterpret_cast<const f32x4*>(xrow + ch * 128 + (j >> 1) * 32 + (j & 1) * 4);

        #pragma unroll
        for (int ktl = 0; ktl < 4; ++ktl) {
            const int kt = ch * 4 + ktl;
            const bf16x8 wv0 = w1l[(kt * 3 + 0) * 64 + l];   // ds_read_b128 (lgkmcnt)
            const bf16x8 wv1 = w1l[(kt * 3 + 1) * 64 + l];
            const bf16x8 wv2 = w1l[(kt * 3 + 2) * 64 + l];
            const f32x4 xa = xv[2 * ktl + 0];
            const f32x4 xb = xv[2 * ktl + 1];
            bf16x8 bf;
            #pragma unroll
            for (int b = 0; b < 4; ++b) {
                if (b & 1) { rs1 += xa[b]; rq1 += xa[b] * xa[b]; rs1 += xb[b]; rq1 += xb[b] * xb[b]; }
                else       { rs0 += xa[b]; rq0 += xa[b] * xa[b]; rs0 += xb[b]; rq0 += xb[b] * xb[b]; }
                bf[b]     = (short)f2bf(xa[b]);
                bf[b + 4] = (short)f2bf(xb[b]);
            }
            acc1[0] = __builtin_amdgcn_mfma_f32_16x16x32_bf16(wv0, bf, acc1[0], 0, 0, 0);
            acc1[1] = __builtin_amdgcn_mfma_f32_16x16x32_bf16(wv1, bf, acc1[1], 0, 0, 0);
            acc1[2] = __builtin_amdgcn_mfma_f32_16x16x32_bf16(wv2, bf, acc1[2], 0, 0, 0);
        }
    }

    float rsum = rs0 + rs1, rsq = rq0 + rq1;
    rsum += __shfl_xor(rsum, 16); rsum += __shfl_xor(rsum, 32);
    rsq  += __shfl_xor(rsq , 16); rsq  += __shfl_xor(rsq , 32);
    const float mu   = rsum * (1.f / 768.f);
    const float var  = rsq * (1.f / 768.f) - mu * mu;
    const float rstd = rsqrtf(var + 1e-5f);

    __syncthreads();   // ALL waves done reading W1 pack -> safe to alias as hid

    // hid tile [4][16][72] bf16 aliases lds_big
    unsigned short* const hid = reinterpret_cast<unsigned short*>(lds_big);
    // zero k-pad cols 48..63 of this wave's tile
    *reinterpret_cast<unsigned long long*>(hid + ((w * 16 + (l >> 2)) * 72) + 48 + (l & 3) * 4) = 0ull;

    // LN fixup + bias + QuickGELU -> hid
    #pragma unroll
    for (int nt = 0; nt < 3; ++nt) {
        const int c4 = nt * 16 + 4 * lg;
        const f32x4 bb = *reinterpret_cast<const f32x4*>(&lds_b1[c4]);
        const f32x4 cs = *reinterpret_cast<const f32x4*>(&lds_cs[c4]);
        u16x4 pk;
        #pragma unroll
        for (int r = 0; r < 4; ++r) {
            const float h = rstd * (acc1[nt][r] - mu * cs[r]) + bb[r];
            const float g = h / (1.f + __expf(-1.702f * h));
            pk[r] = f2bf(g);
        }
        *reinterpret_cast<u16x4*>(hid + (w * 16 + lrow) * 72 + c4) = pk;
    }
    // wave-synchronous LDS handoff (same wave writes+reads; lgkmcnt-ordered)
    const bf16x8 a2_0 = *reinterpret_cast<const bf16x8*>(hid + (w * 16 + lrow) * 72 + 8 * lg);
    const bf16x8 a2_1 = *reinterpret_cast<const bf16x8*>(hid + (w * 16 + lrow) * 72 + 8 * lg + 32);

    const float* __restrict__ xres = x   + (m0 + lrow) * CDIM;
    float* __restrict__       ores = out + (m0 + lrow) * CDIM;

    // ===== GEMM2 (R2-verbatim, measured 4.4 TB/s standalone) =====
    #pragma unroll 1
    for (int ch = 0; ch < 6; ++ch) {
        f32x4 res[8];
        #pragma unroll
        for (int n8 = 0; n8 < 8; ++n8)
            res[n8] = *reinterpret_cast<const f32x4*>(xres + (ch * 8 + n8) * 16 + 4 * lg);
        f32x4 acc2[8];
        #pragma unroll
        for (int n8 = 0; n8 < 8; ++n8) { acc2[n8][0]=0.f; acc2[n8][1]=0.f; acc2[n8][2]=0.f; acc2[n8][3]=0.f; }
        #pragma unroll
        for (int n8 = 0; n8 < 8; ++n8) {
            const int ct = ch * 8 + n8;
            acc2[n8] = __builtin_amdgcn_mfma_f32_16x16x32_bf16(w2f[ct * 64 + l],        a2_0, acc2[n8], 0, 0, 0);
            acc2[n8] = __builtin_amdgcn_mfma_f32_16x16x32_bf16(w2f[(48 + ct) * 64 + l], a2_1, acc2[n8], 0, 0, 0);
        }
        #pragma unroll
        for (int n8 = 0; n8 < 8; ++n8) {
            const int c4 = (ch * 8 + n8) * 16 + 4 * lg;
            const f32x4 bb = *reinterpret_cast<const f32x4*>(&lds_b2[c4]);
            f32x4 o;
            #pragma unroll
            for (int r = 0; r < 4; ++r) o[r] = acc2[n8][r] + bb[r] + res[n8][r];
            *reinterpret_cast<f32x4*>(ores + c4) = o;
        }
    }
}

extern "C" void kernel_launch(void* const* d_in, const int* in_sizes, int n_in,
                              void* d_out, int out_size, void* d_ws, size_t ws_size,
                              hipStream_t stream)
{
    const float* x     = (const float*)d_in[0];
    const float* W1    = (const float*)d_in[1];
    const float* b1    = (const float*)d_in[2];
    const float* W2    = (const float*)d_in[3];
    const float* b2    = (const float*)d_in[4];
    const float* gamma = (const float*)d_in[5];
    const float* beta  = (const float*)d_in[6];
    float* out = (float*)d_out;

    unsigned short* w1p = (unsigned short*)d_ws;     // 72 frags * 512 B  = 73728 B
    unsigned short* w2p = w1p + 24 * 3 * 64 * 8;     // 96 frags * 512 B  = 98304 B
    float* b1p = (float*)(w2p + 2 * 48 * 64 * 8);    // 48 f32
    float* cs1 = b1p + 64;                           // 48 f32 (16B-aligned gap)

    const int M = in_sizes[0] / CDIM;   // 131072 rows
    const int blocks = M / 64;          // 2048 blocks x 4 waves x 16 rows

    prep_kernel<<<dim3(43), dim3(256), 0, stream>>>(W1, b1, W2, gamma, beta, w1p, w2p, b1p, cs1);
    mlp_kernel<<<dim3(blocks), dim3(256), 0, stream>>>(x, b2, w1p, w2p, b1p, cs1, out);
}